// Round 2
// baseline (777.304 us; speedup 1.0000x reference)
//
#include <hip/hip_runtime.h>
#include <math.h>

#define NN 50000
#define NE 800000
#define DIN 128
#define DH 64
#define NG 64

// ---------------- degree histogram ----------------
__global__ void deg_kernel(const int* __restrict__ col, int* __restrict__ indeg, int e) {
    int i = blockIdx.x * blockDim.x + threadIdx.x;
    int stride = gridDim.x * blockDim.x;
    for (; i < e; i += stride) atomicAdd(&indeg[col[i]], 1);
}

// dinv[i] = rsqrt(indeg[i] + 1)   (+1 = self loop; always > 0)
__global__ void dinv_kernel(const int* __restrict__ indeg, float* __restrict__ dinv, int n) {
    int i = blockIdx.x * blockDim.x + threadIdx.x;
    if (i < n) dinv[i] = rsqrtf((float)(indeg[i] + 1));
}

// ---------------- exclusive scan of indeg -> csr_off (single block, chunked wave scan) ----------------
__global__ __launch_bounds__(1024) void scan_kernel(const int* __restrict__ indeg,
                                                    int* __restrict__ off, int n) {
    __shared__ int wsum[16];
    __shared__ int carry_s;
    int tid = threadIdx.x;
    int lane = tid & 63, wid = tid >> 6;
    if (tid == 0) carry_s = 0;
    __syncthreads();
    for (int base = 0; base < n; base += 1024) {
        int i = base + tid;
        int v0 = (i < n) ? indeg[i] : 0;
        int v = v0;
        #pragma unroll
        for (int d = 1; d < 64; d <<= 1) {
            int t = __shfl_up(v, d, 64);
            if (lane >= d) v += t;
        }
        if (lane == 63) wsum[wid] = v;
        __syncthreads();
        if (wid == 0) {
            int wv = (lane < 16) ? wsum[lane] : 0;
            #pragma unroll
            for (int d = 1; d < 16; d <<= 1) {
                int t = __shfl_up(wv, d, 64);
                if (lane >= d) wv += t;
            }
            if (lane < 16) wsum[lane] = wv;
        }
        __syncthreads();
        int woff = (wid == 0) ? 0 : wsum[wid - 1];
        int carry = carry_s;
        if (i < n) off[i] = carry + woff + (v - v0);   // exclusive
        int total = wsum[15];
        __syncthreads();
        if (tid == 0) carry_s = carry + total;
        __syncthreads();
    }
    if (tid == 0) off[n] = carry_s;
}

__global__ void init_cursor_kernel(const int* __restrict__ off, int* __restrict__ cur, int n) {
    int i = blockIdx.x * blockDim.x + threadIdx.x;
    if (i < n) cur[i] = off[i];
}

// bucket edges by target: ew[p] = { bitcast(src), dinv[src]*dinv[col] }
__global__ void fill_kernel(const int* __restrict__ row, const int* __restrict__ col,
                            const float* __restrict__ dinv, int* __restrict__ cursor,
                            float2* __restrict__ ew, int e) {
    int i = blockIdx.x * blockDim.x + threadIdx.x;
    int stride = gridDim.x * blockDim.x;
    for (; i < e; i += stride) {
        int c = col[i], r = row[i];
        int p = atomicAdd(&cursor[c], 1);
        ew[p] = make_float2(__int_as_float(r), dinv[r] * dinv[c]);
    }
}

// ---------------- GEMM: out[N,64] = in[N,K] @ W[K,64]  (no bias; bias fused into pull) ----------------
template <int K>
__global__ __launch_bounds__(256) void gemm_kernel(const float* __restrict__ in,
                                                   const float* __restrict__ W,
                                                   float* __restrict__ out, int n) {
    __shared__ float Ws[K * 64];
    for (int t = threadIdx.x; t < K * 64; t += 256) Ws[t] = W[t];
    __syncthreads();
    int r = threadIdx.x >> 6, j = threadIdx.x & 63;
    int node = blockIdx.x * 4 + r;
    if (node >= n) return;
    const float* inr = in + (size_t)node * K;
    float acc = 0.f;
    #pragma unroll
    for (int k = 0; k < K; k += 4) {
        float4 xv = *reinterpret_cast<const float4*>(inr + k);
        acc = fmaf(xv.x, Ws[(k + 0) * 64 + j], acc);
        acc = fmaf(xv.y, Ws[(k + 1) * 64 + j], acc);
        acc = fmaf(xv.z, Ws[(k + 2) * 64 + j], acc);
        acc = fmaf(xv.w, Ws[(k + 3) * 64 + j], acc);
    }
    out[(size_t)node * 64 + j] = acc;
}

// ---------------- pull aggregation + bias + ELU: one wave per node, lane = feature ----------------
// Unrolled x4: issue 4 metadata loads + 4 row gathers before consuming -> 4 outstanding
// VMEM ops per wave (latency hiding), instead of a serial dependent chain.
__global__ __launch_bounds__(256) void pull_kernel(const float* __restrict__ tmp,
                                                   const int* __restrict__ off,
                                                   const float2* __restrict__ ew,
                                                   const float* __restrict__ dinv,
                                                   const float* __restrict__ bias,
                                                   float* __restrict__ out, int n) {
    int wid = threadIdx.x >> 6;
    int lane = threadIdx.x & 63;
    int node = blockIdx.x * 4 + wid;
    if (node >= n) return;
    float dt = dinv[node];
    float acc = tmp[(size_t)node * 64 + lane] * dt * dt;   // self loop
    int e = off[node], s1 = off[node + 1];
    for (; e + 4 <= s1; e += 4) {
        float2 m0 = ew[e + 0];
        float2 m1 = ew[e + 1];
        float2 m2 = ew[e + 2];
        float2 m3 = ew[e + 3];
        float v0 = tmp[(size_t)__float_as_int(m0.x) * 64 + lane];
        float v1 = tmp[(size_t)__float_as_int(m1.x) * 64 + lane];
        float v2 = tmp[(size_t)__float_as_int(m2.x) * 64 + lane];
        float v3 = tmp[(size_t)__float_as_int(m3.x) * 64 + lane];
        acc = fmaf(v0, m0.y, acc);
        acc = fmaf(v1, m1.y, acc);
        acc = fmaf(v2, m2.y, acc);
        acc = fmaf(v3, m3.y, acc);
    }
    for (; e < s1; ++e) {
        float2 m = ew[e];
        acc = fmaf(tmp[(size_t)__float_as_int(m.x) * 64 + lane], m.y, acc);
    }
    float v = acc + bias[lane];
    out[(size_t)node * 64 + lane] = (v > 0.f) ? v : expm1f(v);
}

// ---------------- final linear + grouped mean-pool partials ----------------
__global__ __launch_bounds__(256) void final_pool_kernel(const float* __restrict__ h,
                                                         const float* __restrict__ Wl,
                                                         const int* __restrict__ batch,
                                                         float* __restrict__ gsum,
                                                         float* __restrict__ gcnt, int n) {
    __shared__ float lsum[NG];
    __shared__ float lcnt[NG];
    if (threadIdx.x < NG) { lsum[threadIdx.x] = 0.f; lcnt[threadIdx.x] = 0.f; }
    __syncthreads();
    int wid = threadIdx.x >> 6, lane = threadIdx.x & 63;
    int node = blockIdx.x * 4 + wid;
    if (node < n) {
        float p = h[(size_t)node * 64 + lane] * Wl[lane];
        #pragma unroll
        for (int d = 32; d >= 1; d >>= 1) p += __shfl_xor(p, d, 64);
        if (lane == 0) {
            int g = batch[node];
            atomicAdd(&lsum[g], p);
            atomicAdd(&lcnt[g], 1.f);
        }
    }
    __syncthreads();
    if (threadIdx.x < NG) {
        atomicAdd(&gsum[threadIdx.x], lsum[threadIdx.x]);
        atomicAdd(&gcnt[threadIdx.x], lcnt[threadIdx.x]);
    }
}

__global__ void pool_div_kernel(const float* __restrict__ gsum, const float* __restrict__ gcnt,
                                const float* __restrict__ bl, float* __restrict__ out) {
    int g = threadIdx.x;
    if (g < NG) {
        float c = gcnt[g];
        out[g] = (c > 0.5f) ? (gsum[g] / c + bl[0]) : 0.f;
    }
}

extern "C" void kernel_launch(void* const* d_in, const int* in_sizes, int n_in,
                              void* d_out, int out_size, void* d_ws, size_t ws_size,
                              hipStream_t stream) {
    const float* x    = (const float*)d_in[0];
    const int*   eidx = (const int*)d_in[1];
    const int*   row  = eidx;              // edge_index[0] = sources
    const int*   col  = eidx + NE;         // edge_index[1] = targets
    const int*   batch = (const int*)d_in[2];
    const float* W1 = (const float*)d_in[3];
    const float* b1 = (const float*)d_in[4];
    const float* W2 = (const float*)d_in[5];
    const float* b2 = (const float*)d_in[6];
    const float* W3 = (const float*)d_in[7];
    const float* b3 = (const float*)d_in[8];
    const float* Wl = (const float*)d_in[9];
    const float* bl = (const float*)d_in[10];
    float* out = (float*)d_out;

    // workspace layout (all offsets 64-element = 256B aligned)
    size_t cur = 0;
    auto take = [&](size_t elems) { size_t c = cur; cur += (elems + 63) & ~(size_t)63; return c; };
    float* base_f = (float*)d_ws;
    int*   base_i = (int*)d_ws;

    float*  dinv    = base_f + take(NN);
    int*    indeg   = base_i + take(NN);
    int*    csr_off = base_i + take(NN + 1);
    int*    cursor  = base_i + take(NN);
    float2* ew      = (float2*)(base_f + take((size_t)NE * 2));
    float*  tmp     = base_f + take((size_t)NN * 64);
    float*  h       = base_f + take((size_t)NN * 64);
    float*  gsum    = base_f + take(NG);
    float*  gcnt    = base_f + take(NG);
    (void)ws_size; (void)n_in; (void)in_sizes; (void)out_size;

    // ---- CSR build ----
    hipMemsetAsync(indeg, 0, NN * sizeof(int), stream);
    hipMemsetAsync(gsum, 0, NG * sizeof(float), stream);
    hipMemsetAsync(gcnt, 0, NG * sizeof(float), stream);

    deg_kernel<<<1024, 256, 0, stream>>>(col, indeg, NE);
    dinv_kernel<<<(NN + 255) / 256, 256, 0, stream>>>(indeg, dinv, NN);
    scan_kernel<<<1, 1024, 0, stream>>>(indeg, csr_off, NN);
    init_cursor_kernel<<<(NN + 255) / 256, 256, 0, stream>>>(csr_off, cursor, NN);
    fill_kernel<<<1024, 256, 0, stream>>>(row, col, dinv, cursor, ew, NE);

    const int nblk = (NN + 3) / 4;   // 4 nodes per 256-thread block

    // ---- layer 1: tmp = x @ W1 ; h = elu(pull(tmp) + b1) ----
    gemm_kernel<DIN><<<nblk, 256, 0, stream>>>(x, W1, tmp, NN);
    pull_kernel<<<nblk, 256, 0, stream>>>(tmp, csr_off, ew, dinv, b1, h, NN);

    // ---- layer 2 ----
    gemm_kernel<DH><<<nblk, 256, 0, stream>>>(h, W2, tmp, NN);
    pull_kernel<<<nblk, 256, 0, stream>>>(tmp, csr_off, ew, dinv, b2, h, NN);

    // ---- layer 3 ----
    gemm_kernel<DH><<<nblk, 256, 0, stream>>>(h, W3, tmp, NN);
    pull_kernel<<<nblk, 256, 0, stream>>>(tmp, csr_off, ew, dinv, b3, h, NN);

    // ---- final linear + mean pool ----
    final_pool_kernel<<<nblk, 256, 0, stream>>>(h, Wl, batch, gsum, gcnt, NN);
    pool_div_kernel<<<1, 64, 0, stream>>>(gsum, gcnt, bl, out);
}

// Round 3
// 498.615 us; speedup vs baseline: 1.5589x; 1.5589x over previous
//
#include <hip/hip_runtime.h>
#include <math.h>

#define NN 50000
#define NE 800000
#define DIN 128
#define DH 64
#define NG 64

// ---------------- degree histogram ----------------
__global__ void deg_kernel(const int* __restrict__ col, int* __restrict__ indeg, int e) {
    int i = blockIdx.x * blockDim.x + threadIdx.x;
    int stride = gridDim.x * blockDim.x;
    for (; i < e; i += stride) atomicAdd(&indeg[col[i]], 1);
}

// dinv[i] = rsqrt(indeg[i] + 1)   (+1 = self loop; always > 0)
__global__ void dinv_kernel(const int* __restrict__ indeg, float* __restrict__ dinv, int n) {
    int i = blockIdx.x * blockDim.x + threadIdx.x;
    if (i < n) dinv[i] = rsqrtf((float)(indeg[i] + 1));
}

// ---------------- exclusive scan of indeg -> csr_off (single block, chunked wave scan) ----------------
__global__ __launch_bounds__(1024) void scan_kernel(const int* __restrict__ indeg,
                                                    int* __restrict__ off, int n) {
    __shared__ int wsum[16];
    __shared__ int carry_s;
    int tid = threadIdx.x;
    int lane = tid & 63, wid = tid >> 6;
    if (tid == 0) carry_s = 0;
    __syncthreads();
    for (int base = 0; base < n; base += 1024) {
        int i = base + tid;
        int v0 = (i < n) ? indeg[i] : 0;
        int v = v0;
        #pragma unroll
        for (int d = 1; d < 64; d <<= 1) {
            int t = __shfl_up(v, d, 64);
            if (lane >= d) v += t;
        }
        if (lane == 63) wsum[wid] = v;
        __syncthreads();
        if (wid == 0) {
            int wv = (lane < 16) ? wsum[lane] : 0;
            #pragma unroll
            for (int d = 1; d < 16; d <<= 1) {
                int t = __shfl_up(wv, d, 64);
                if (lane >= d) wv += t;
            }
            if (lane < 16) wsum[lane] = wv;
        }
        __syncthreads();
        int woff = (wid == 0) ? 0 : wsum[wid - 1];
        int carry = carry_s;
        if (i < n) off[i] = carry + woff + (v - v0);   // exclusive
        int total = wsum[15];
        __syncthreads();
        if (tid == 0) carry_s = carry + total;
        __syncthreads();
    }
    if (tid == 0) off[n] = carry_s;
}

__global__ void init_cursor_kernel(const int* __restrict__ off, int* __restrict__ cur, int n) {
    int i = blockIdx.x * blockDim.x + threadIdx.x;
    if (i < n) cur[i] = off[i];
}

// bucket edges by target: ew[p] = { bitcast(src), dinv[src]*dinv[col] }
__global__ void fill_kernel(const int* __restrict__ row, const int* __restrict__ col,
                            const float* __restrict__ dinv, int* __restrict__ cursor,
                            float2* __restrict__ ew, int e) {
    int i = blockIdx.x * blockDim.x + threadIdx.x;
    int stride = gridDim.x * blockDim.x;
    for (; i < e; i += stride) {
        int c = col[i], r = row[i];
        int p = atomicAdd(&cursor[c], 1);
        ew[p] = make_float2(__int_as_float(r), dinv[r] * dinv[c]);
    }
}

// ---------------- GEMM: out[N,64] = in[N,K] @ W[K,64]  (no bias; bias fused into pull) ----------------
template <int K>
__global__ __launch_bounds__(256) void gemm_kernel(const float* __restrict__ in,
                                                   const float* __restrict__ W,
                                                   float* __restrict__ out, int n) {
    __shared__ float Ws[K * 64];
    for (int t = threadIdx.x; t < K * 64; t += 256) Ws[t] = W[t];
    __syncthreads();
    int r = threadIdx.x >> 6, j = threadIdx.x & 63;
    int node = blockIdx.x * 4 + r;
    if (node >= n) return;
    const float* inr = in + (size_t)node * K;
    float acc = 0.f;
    #pragma unroll
    for (int k = 0; k < K; k += 4) {
        float4 xv = *reinterpret_cast<const float4*>(inr + k);
        acc = fmaf(xv.x, Ws[(k + 0) * 64 + j], acc);
        acc = fmaf(xv.y, Ws[(k + 1) * 64 + j], acc);
        acc = fmaf(xv.z, Ws[(k + 2) * 64 + j], acc);
        acc = fmaf(xv.w, Ws[(k + 3) * 64 + j], acc);
    }
    out[(size_t)node * 64 + j] = acc;
}

// ---------------- pull aggregation + bias + ELU: one wave per node, lane = feature ----------------
__global__ __launch_bounds__(256) void pull_kernel(const float* __restrict__ tmp,
                                                   const int* __restrict__ off,
                                                   const float2* __restrict__ ew,
                                                   const float* __restrict__ dinv,
                                                   const float* __restrict__ bias,
                                                   float* __restrict__ out, int n) {
    int wid = threadIdx.x >> 6;
    int lane = threadIdx.x & 63;
    int node = blockIdx.x * 4 + wid;
    if (node >= n) return;
    float dt = dinv[node];
    float acc = tmp[(size_t)node * 64 + lane] * dt * dt;   // self loop
    int e = off[node], s1 = off[node + 1];
    for (; e + 4 <= s1; e += 4) {
        float2 m0 = ew[e + 0];
        float2 m1 = ew[e + 1];
        float2 m2 = ew[e + 2];
        float2 m3 = ew[e + 3];
        float v0 = tmp[(size_t)__float_as_int(m0.x) * 64 + lane];
        float v1 = tmp[(size_t)__float_as_int(m1.x) * 64 + lane];
        float v2 = tmp[(size_t)__float_as_int(m2.x) * 64 + lane];
        float v3 = tmp[(size_t)__float_as_int(m3.x) * 64 + lane];
        acc = fmaf(v0, m0.y, acc);
        acc = fmaf(v1, m1.y, acc);
        acc = fmaf(v2, m2.y, acc);
        acc = fmaf(v3, m3.y, acc);
    }
    for (; e < s1; ++e) {
        float2 m = ew[e];
        acc = fmaf(tmp[(size_t)__float_as_int(m.x) * 64 + lane], m.y, acc);
    }
    float v = acc + bias[lane];
    out[(size_t)node * 64 + lane] = (v > 0.f) ? v : expm1f(v);
}

// ---------------- final linear + grouped mean-pool partials ----------------
// 256 blocks, each owning a CONTIGUOUS node chunk. batch is sorted, so each
// chunk touches ~1-2 graphs: LDS accumulation across the whole chunk, then a
// sparse flush (skip zero-count graphs) -> ~1K global atomics total instead of
// 1.6M (which serialized at 303us in round 2).
#define POOL_BLOCKS 256
__global__ __launch_bounds__(256) void final_pool_kernel(const float* __restrict__ h,
                                                         const float* __restrict__ Wl,
                                                         const int* __restrict__ batch,
                                                         float* __restrict__ gsum,
                                                         float* __restrict__ gcnt, int n) {
    __shared__ float lsum[NG];
    __shared__ float lcnt[NG];
    if (threadIdx.x < NG) { lsum[threadIdx.x] = 0.f; lcnt[threadIdx.x] = 0.f; }
    __syncthreads();
    int wid = threadIdx.x >> 6, lane = threadIdx.x & 63;
    float wl = Wl[lane];
    int per_block = (n + POOL_BLOCKS - 1) / POOL_BLOCKS;
    int start = blockIdx.x * per_block;
    int end = start + per_block;
    if (end > n) end = n;
    for (int node = start + wid; node < end; node += 4) {
        float p = h[(size_t)node * 64 + lane] * wl;
        #pragma unroll
        for (int d = 32; d >= 1; d >>= 1) p += __shfl_xor(p, d, 64);
        if (lane == 0) {
            int g = batch[node];
            atomicAdd(&lsum[g], p);
            atomicAdd(&lcnt[g], 1.f);
        }
    }
    __syncthreads();
    if (threadIdx.x < NG && lcnt[threadIdx.x] != 0.f) {
        atomicAdd(&gsum[threadIdx.x], lsum[threadIdx.x]);
        atomicAdd(&gcnt[threadIdx.x], lcnt[threadIdx.x]);
    }
}

__global__ void pool_div_kernel(const float* __restrict__ gsum, const float* __restrict__ gcnt,
                                const float* __restrict__ bl, float* __restrict__ out) {
    int g = threadIdx.x;
    if (g < NG) {
        float c = gcnt[g];
        out[g] = (c > 0.5f) ? (gsum[g] / c + bl[0]) : 0.f;
    }
}

extern "C" void kernel_launch(void* const* d_in, const int* in_sizes, int n_in,
                              void* d_out, int out_size, void* d_ws, size_t ws_size,
                              hipStream_t stream) {
    const float* x    = (const float*)d_in[0];
    const int*   eidx = (const int*)d_in[1];
    const int*   row  = eidx;              // edge_index[0] = sources
    const int*   col  = eidx + NE;         // edge_index[1] = targets
    const int*   batch = (const int*)d_in[2];
    const float* W1 = (const float*)d_in[3];
    const float* b1 = (const float*)d_in[4];
    const float* W2 = (const float*)d_in[5];
    const float* b2 = (const float*)d_in[6];
    const float* W3 = (const float*)d_in[7];
    const float* b3 = (const float*)d_in[8];
    const float* Wl = (const float*)d_in[9];
    const float* bl = (const float*)d_in[10];
    float* out = (float*)d_out;

    // workspace layout (all offsets 64-element = 256B aligned)
    size_t cur = 0;
    auto take = [&](size_t elems) { size_t c = cur; cur += (elems + 63) & ~(size_t)63; return c; };
    float* base_f = (float*)d_ws;
    int*   base_i = (int*)d_ws;

    float*  dinv    = base_f + take(NN);
    int*    indeg   = base_i + take(NN);
    int*    csr_off = base_i + take(NN + 1);
    int*    cursor  = base_i + take(NN);
    float2* ew      = (float2*)(base_f + take((size_t)NE * 2));
    float*  tmp     = base_f + take((size_t)NN * 64);
    float*  h       = base_f + take((size_t)NN * 64);
    float*  gsum    = base_f + take(NG);
    float*  gcnt    = base_f + take(NG);
    (void)ws_size; (void)n_in; (void)in_sizes; (void)out_size;

    // ---- CSR build ----
    hipMemsetAsync(indeg, 0, NN * sizeof(int), stream);
    hipMemsetAsync(gsum, 0, NG * sizeof(float), stream);
    hipMemsetAsync(gcnt, 0, NG * sizeof(float), stream);

    deg_kernel<<<1024, 256, 0, stream>>>(col, indeg, NE);
    dinv_kernel<<<(NN + 255) / 256, 256, 0, stream>>>(indeg, dinv, NN);
    scan_kernel<<<1, 1024, 0, stream>>>(indeg, csr_off, NN);
    init_cursor_kernel<<<(NN + 255) / 256, 256, 0, stream>>>(csr_off, cursor, NN);
    fill_kernel<<<1024, 256, 0, stream>>>(row, col, dinv, cursor, ew, NE);

    const int nblk = (NN + 3) / 4;   // 4 nodes per 256-thread block

    // ---- layer 1: tmp = x @ W1 ; h = elu(pull(tmp) + b1) ----
    gemm_kernel<DIN><<<nblk, 256, 0, stream>>>(x, W1, tmp, NN);
    pull_kernel<<<nblk, 256, 0, stream>>>(tmp, csr_off, ew, dinv, b1, h, NN);

    // ---- layer 2 ----
    gemm_kernel<DH><<<nblk, 256, 0, stream>>>(h, W2, tmp, NN);
    pull_kernel<<<nblk, 256, 0, stream>>>(tmp, csr_off, ew, dinv, b2, h, NN);

    // ---- layer 3 ----
    gemm_kernel<DH><<<nblk, 256, 0, stream>>>(h, W3, tmp, NN);
    pull_kernel<<<nblk, 256, 0, stream>>>(tmp, csr_off, ew, dinv, b3, h, NN);

    // ---- final linear + mean pool ----
    final_pool_kernel<<<POOL_BLOCKS, 256, 0, stream>>>(h, Wl, batch, gsum, gcnt, NN);
    pool_div_kernel<<<1, 64, 0, stream>>>(gsum, gcnt, bl, out);
}